// Round 1
// 3237.140 us; speedup vs baseline: 1.2061x; 1.2061x over previous
//
#include <hip/hip_runtime.h>
#include <hip/hip_bf16.h>
#include <stdint.h>

typedef __hip_bfloat16 bf16;
typedef __attribute__((ext_vector_type(4))) float f32x4;
typedef __attribute__((ext_vector_type(8))) short bf16x8;

#define K_DIM 256

// async global->LDS, 16B per lane, wave-uniform LDS base + lane*16 placement.
// Global source address is PER-LANE -> we permute sources to implement an
// XOR-swizzled LDS layout: logical chunk (row, cb) lives at (row, cb^(row&7)).
__device__ __forceinline__ void gl2lds16(const void* g, void* l) {
  __builtin_amdgcn_global_load_lds(
      (const __attribute__((address_space(1))) unsigned int*)g,
      (__attribute__((address_space(3))) unsigned int*)l,
      16, 0, 0);
}

// ---------------- embedding: weighted sums -> sv=[subj|verb], vo=[verb|obj] (bf16) ----------------
__global__ void embed_kernel(const int* __restrict__ sid, const float* __restrict__ sw,
                             const int* __restrict__ vid, const float* __restrict__ vw,
                             const int* __restrict__ oid, const float* __restrict__ ow,
                             const float* __restrict__ emb,
                             bf16* __restrict__ sv, bf16* __restrict__ vo) {
  int b = blockIdx.x;
  int t = threadIdx.x;
  float s0 = 0.f, s1 = 0.f, v0 = 0.f, v1 = 0.f, o0 = 0.f, o1 = 0.f;
#pragma unroll
  for (int n = 0; n < 8; ++n) {
    int i0 = b * 8 + n;
    { int id = sid[i0]; float w = sw[i0]; const float* r = emb + (size_t)id * 512; s0 += w * r[t]; s1 += w * r[t + 256]; }
    { int id = vid[i0]; float w = vw[i0]; const float* r = emb + (size_t)id * 512; v0 += w * r[t]; v1 += w * r[t + 256]; }
    { int id = oid[i0]; float w = ow[i0]; const float* r = emb + (size_t)id * 512; o0 += w * r[t]; o1 += w * r[t + 256]; }
  }
  size_t base = (size_t)b * 1024;
  bf16 vb0 = __float2bfloat16(v0), vb1 = __float2bfloat16(v1);
  sv[base + t]       = __float2bfloat16(s0);
  sv[base + 256 + t] = __float2bfloat16(s1);
  sv[base + 512 + t] = vb0;
  sv[base + 768 + t] = vb1;
  vo[base + t]       = vb0;
  vo[base + 256 + t] = vb1;
  vo[base + 512 + t] = __float2bfloat16(o0);
  vo[base + 768 + t] = __float2bfloat16(o1);
}

// ---------------- elementwise fp32 -> bf16 ----------------
__global__ void cvt_kernel(const float* __restrict__ in, bf16* __restrict__ out, int n) {
  int i = blockIdx.x * blockDim.x + threadIdx.x;
  if (i < n) out[i] = __float2bfloat16(in[i]);
}

// ---------------- per-k transpose + cvt: out[k][j][i] = in[k][i][j] ----------------
__global__ void tcvt_kernel(const float* __restrict__ in, bf16* __restrict__ out, int N) {
  __shared__ float tile[32][33];
  int k = blockIdx.z;
  size_t base = (size_t)k * N * N;
  int j0 = blockIdx.x * 32, i0 = blockIdx.y * 32;
  int tx = threadIdx.x, ty = threadIdx.y;
#pragma unroll
  for (int r = 0; r < 4; ++r)
    tile[ty + 8 * r][tx] = in[base + (size_t)(i0 + ty + 8 * r) * N + j0 + tx];
  __syncthreads();
#pragma unroll
  for (int r = 0; r < 4; ++r)
    out[base + (size_t)(j0 + ty + 8 * r) * N + i0 + tx] = __float2bfloat16(tile[tx][ty + 8 * r]);
}

// ---------------- linear term: L[b,kc] = sum_i A[b,i]*W[kc,i] + bias[kc] (fp32 out) ----------------
// grid (B/128, 256/64), block 256. A row stride == inner. XOR-swizzled LDS.
__global__ __launch_bounds__(256) void lin_kernel(
    const bf16* __restrict__ A, const bf16* __restrict__ W,
    const float* __restrict__ bias, float* __restrict__ Lout, int inner) {
  __shared__ __align__(16) bf16 As[128 * 64];
  __shared__ __align__(16) bf16 Bs[64 * 64];
  int tid = threadIdx.x;
  int wv = tid >> 6, lane = tid & 63;
  int wr = wv >> 1, wc = wv & 1;
  int cl = lane & 15, rg = lane >> 4;
  int r8 = lane >> 3, c8 = lane & 7;
  int cs = c8 ^ r8;                      // swizzled source column-block
  int b0 = blockIdx.x * 128;
  int n0 = blockIdx.y * 64;
  f32x4 acc[4][2] = {};
  int KO = inner >> 6;
  for (int ko = 0; ko < KO; ++ko) {
    __syncthreads();
#pragma unroll
    for (int it = 0; it < 4; ++it) {
      int m = wv * 32 + it * 8 + r8;
      gl2lds16(A + (size_t)(b0 + m) * inner + ko * 64 + cs * 8, &As[(wv * 32 + it * 8) * 64]);
    }
#pragma unroll
    for (int it = 0; it < 2; ++it) {
      int nn = wv * 16 + it * 8 + r8;
      gl2lds16(W + (size_t)(n0 + nn) * inner + ko * 64 + cs * 8, &Bs[(wv * 16 + it * 8) * 64]);
    }
    __syncthreads();
#pragma unroll
    for (int ks = 0; ks < 2; ++ks) {
      bf16x8 a[4], bb[2];
      int sw = (ks * 4 + rg) ^ (cl & 7);  // physical column-block for logical (ks,rg)
#pragma unroll
      for (int mt = 0; mt < 4; ++mt) a[mt] = *(const bf16x8*)&As[(wr * 64 + mt * 16 + cl) * 64 + sw * 8];
#pragma unroll
      for (int nt = 0; nt < 2; ++nt) bb[nt] = *(const bf16x8*)&Bs[(wc * 32 + nt * 16 + cl) * 64 + sw * 8];
#pragma unroll
      for (int mt = 0; mt < 4; ++mt)
#pragma unroll
        for (int nt = 0; nt < 2; ++nt)
          acc[mt][nt] = __builtin_amdgcn_mfma_f32_16x16x32_bf16(a[mt], bb[nt], acc[mt][nt], 0, 0, 0);
    }
  }
#pragma unroll
  for (int mt = 0; mt < 4; ++mt)
#pragma unroll
    for (int nt = 0; nt < 2; ++nt) {
      int col = n0 + wc * 32 + nt * 16 + cl;
      float bv = bias[col];
#pragma unroll
      for (int r = 0; r < 4; ++r) {
        int row = b0 + wr * 64 + mt * 16 + rg * 4 + r;
        Lout[(size_t)row * K_DIM + col] = acc[mt][nt][r] + bv;
      }
    }
}

// ---------------- fused bilinear, 256x256 tile, pipelined staging ----------------
// out[b,k] = tanh( sum_j (sum_i A[b,i]*T[k,j,i]) * V[b,j] + L[b,k] )
// grid (B/256, K), block 512 (8 waves, 2Mx4N; each wave owns 128x64 of the
// 256x256 U-tile). BK=64, double-buffered LDS (128KB) + 4KB reduction scratch.
// Schedule (T3-minimum): stage step t+1 DURING step t's two MFMA phases; a
// single __syncthreads() per K-step is both the vmcnt(0) visibility fence for
// global_load_lds data and the buffer-reuse barrier -- the drain is covered by
// a full K-step (~2500 cy) of MFMA instead of zero (the old kernel drained
// immediately after issue -> MfmaUtil 15%).
__global__ __launch_bounds__(512) void bilin256_kernel(
    const bf16* __restrict__ A, int lda,
    const bf16* __restrict__ T,          // [K][J][I] (transposed slices, bf16)
    const bf16* __restrict__ V, int ldv, int voff,
    const float* __restrict__ Lm,
    int I, int J, int koshift,           // KO = I/64 = 1<<koshift
    bf16* __restrict__ outb, int ldo, int ooff,
    float* __restrict__ outf) {
  __shared__ __align__(16) bf16 As[2][256 * 64];
  __shared__ __align__(16) bf16 Bs[2][256 * 64];
  __shared__ float scratch[4][256];      // per-wc partial row sums (single writer/slot)

  const int tid  = threadIdx.x;
  const int wv   = tid >> 6;
  const int lane = tid & 63;
  const int wr   = wv >> 2;              // 0..1: row half (128 rows)
  const int wc   = wv & 3;               // 0..3: col quarter (64 cols)
  const int cl   = lane & 15;
  const int rg   = lane >> 4;
  const int c8   = lane & 7;
  const int r8   = lane >> 3;            // 0..7
  const int cs   = c8 ^ r8;              // swizzled source chunk (row&7 == r8)
  const int b0   = blockIdx.x * 256;
  const int k    = blockIdx.y;
  const bf16* Tk = T + (size_t)k * J * I;
  const int KOm  = (1 << koshift) - 1;
  const int NT   = (J >> 8) << koshift;  // total K-steps = JB*KO

  // stage one 128-row half-tile (q=0,1: A halves; q=2,3: B halves) of step s.
  // dest is wave-uniform base (rows p*64 + wv*8), HW adds lane*16B; per-lane
  // source row = +r8, chunk = cs -> LDS holds logical chunk c at phys c^(row&7).
  auto stage_half = [&](int s, int q) {
    const int db   = s & 1;
    const int ko_s = s & KOm;
    const int jb_s = s >> koshift;
    const int hrow = (q & 1) * 128;
#pragma unroll
    for (int p = 0; p < 2; ++p) {
      const int rloc = hrow + p * 64 + wv * 8 + r8;
      if (q < 2)
        gl2lds16(A + (size_t)(b0 + rloc) * lda + ko_s * 64 + cs * 8,
                 &As[db][(hrow + p * 64 + wv * 8) * 64]);
      else
        gl2lds16(Tk + (size_t)(jb_s * 256 + rloc) * I + ko_s * 64 + cs * 8,
                 &Bs[db][(hrow + p * 64 + wv * 8) * 64]);
    }
  };

  const f32x4 zero4 = {0.f, 0.f, 0.f, 0.f};
  f32x4 acc[8][4];

  // prologue: stage step 0 (4 half-tiles, 8 loads/thread)
#pragma unroll
  for (int q = 0; q < 4; ++q) stage_half(0, q);

  for (int t = 0; t < NT; ++t) {
    __syncthreads();                     // vmcnt(0)+lgkmcnt(0)+barrier: buf[t&1] ready,
                                         // all waves' reads of buf[(t+1)&1] done
    const int db = t & 1;
    const int ko = t & KOm;
    const int jb = t >> koshift;
    if (ko == 0) {
#pragma unroll
      for (int m = 0; m < 8; ++m)
#pragma unroll
        for (int n = 0; n < 4; ++n) acc[m][n] = zero4;
    }
    const int s = t + 1;
    const bool hasNext = (s < NT);
#pragma unroll
    for (int ph = 0; ph < 2; ++ph) {     // ks = ph (k-chunk halves of BK=64)
      if (hasNext) { stage_half(s, ph * 2); stage_half(s, ph * 2 + 1); }
      const int sw = (ph * 4 + rg) ^ c8; // physical chunk for logical (ph,rg)
      bf16x8 a[8], bb[4];
#pragma unroll
      for (int mt = 0; mt < 8; ++mt)
        a[mt] = *(const bf16x8*)&As[db][(wr * 128 + mt * 16 + cl) * 64 + sw * 8];
#pragma unroll
      for (int nt = 0; nt < 4; ++nt)
        bb[nt] = *(const bf16x8*)&Bs[db][(wc * 64 + nt * 16 + cl) * 64 + sw * 8];
      __builtin_amdgcn_s_setprio(1);
#pragma unroll
      for (int mt = 0; mt < 8; ++mt)
#pragma unroll
        for (int nt = 0; nt < 4; ++nt)
          acc[mt][nt] = __builtin_amdgcn_mfma_f32_16x16x32_bf16(a[mt], bb[nt], acc[mt][nt], 0, 0, 0);
      __builtin_amdgcn_s_setprio(0);
    }
    if (ko == KOm) {
      // fold V: rsum[row] += sum_cols U[row,col]*V[row,col]; next-jb stage
      // loads are already in flight underneath this epilogue.
#pragma unroll
      for (int m = 0; m < 8; ++m) {
#pragma unroll
        for (int r = 0; r < 4; ++r) {
          const int row = wr * 128 + m * 16 + rg * 4 + r;
          const bf16* vrow = V + (size_t)(b0 + row) * ldv + voff + jb * 256 + wc * 64 + cl;
          float x = acc[m][0][r] * __bfloat162float(vrow[0])
                  + acc[m][1][r] * __bfloat162float(vrow[16])
                  + acc[m][2][r] * __bfloat162float(vrow[32])
                  + acc[m][3][r] * __bfloat162float(vrow[48]);
          x += __shfl_xor(x, 1);
          x += __shfl_xor(x, 2);
          x += __shfl_xor(x, 4);
          x += __shfl_xor(x, 8);
          if (cl == 0) {                 // one writer per (wc,row) slot
            if (jb == 0) scratch[wc][row] = x;
            else         scratch[wc][row] += x;
          }
        }
      }
    }
  }
  __syncthreads();
  if (tid < 256) {
    const int gb = b0 + tid;
    const float sum = scratch[0][tid] + scratch[1][tid] + scratch[2][tid] + scratch[3][tid]
                    + Lm[(size_t)gb * K_DIM + k];
    const float tv = tanhf(sum);
    if (outb) outb[(size_t)gb * ldo + ooff + k] = __float2bfloat16(tv);
    else      outf[(size_t)gb * K_DIM + k] = tv;
  }
}

extern "C" void kernel_launch(void* const* d_in, const int* in_sizes, int n_in,
                              void* d_out, int out_size, void* d_ws, size_t ws_size,
                              hipStream_t stream) {
  const int*   sid = (const int*)d_in[0];
  const float* sw  = (const float*)d_in[1];
  const int*   vid = (const int*)d_in[2];
  const float* vw  = (const float*)d_in[3];
  const int*   oid = (const int*)d_in[4];
  const float* ow  = (const float*)d_in[5];
  const float* emb = (const float*)d_in[6];
  const float* t1  = (const float*)d_in[7];
  const float* t2  = (const float*)d_in[8];
  const float* t3  = (const float*)d_in[9];
  const float* W1  = (const float*)d_in[10];
  const float* b1  = (const float*)d_in[11];
  const float* W2  = (const float*)d_in[12];
  const float* b2  = (const float*)d_in[13];
  const float* W3  = (const float*)d_in[14];
  const float* b3  = (const float*)d_in[15];

  char* ws = (char*)d_ws;
  // layout (bytes): Tbuf reused sequentially for t1b/t2b/t3b
  bf16*  Tbuf = (bf16*)(ws);                      // 134217728
  bf16*  W1b  = (bf16*)(ws + 134217728ull);       // 524288
  bf16*  W2b  = (bf16*)(ws + 134742016ull);       // 524288
  bf16*  W3b  = (bf16*)(ws + 135266304ull);       // 262144
  bf16*  sv   = (bf16*)(ws + 135528448ull);       // 8388608  [subj|verb] bf16 (B x 1024)
  bf16*  vo   = (bf16*)(ws + 143917056ull);       // 8388608  [verb|obj]
  float* Lb   = (float*)(ws + 152305664ull);      // 4194304  shared L1/L2/L3
  bf16*  r12  = (bf16*)(ws + 156499968ull);       // 4194304  [r1|r2] bf16 (B x 512)
  // total: 160694272 bytes (~153 MB)

  embed_kernel<<<4096, 256, 0, stream>>>(sid, sw, vid, vw, oid, ow, emb, sv, vo);
  cvt_kernel<<<1024, 256, 0, stream>>>(W1, W1b, 256 * 1024);
  cvt_kernel<<<1024, 256, 0, stream>>>(W2, W2b, 256 * 1024);
  cvt_kernel<<<512, 256, 0, stream>>>(W3, W3b, 256 * 512);

  // stage 1: r1
  lin_kernel<<<dim3(32, 4), 256, 0, stream>>>(sv, W1b, b1, Lb, 1024);
  tcvt_kernel<<<dim3(16, 16, 256), dim3(32, 8), 0, stream>>>(t1, Tbuf, 512);
  bilin256_kernel<<<dim3(16, 256), 512, 0, stream>>>(sv, 1024, Tbuf, sv, 1024, 512, Lb,
                                                     512, 512, 3, r12, 512, 0, nullptr);
  // stage 2: r2
  lin_kernel<<<dim3(32, 4), 256, 0, stream>>>(vo, W2b, b2, Lb, 1024);
  tcvt_kernel<<<dim3(16, 16, 256), dim3(32, 8), 0, stream>>>(t2, Tbuf, 512);
  bilin256_kernel<<<dim3(16, 256), 512, 0, stream>>>(vo, 1024, Tbuf, vo, 1024, 512, Lb,
                                                     512, 512, 3, r12, 512, 256, nullptr);
  // stage 3: r3 -> d_out (fp32)
  lin_kernel<<<dim3(32, 4), 256, 0, stream>>>(r12, W3b, b3, Lb, 512);
  tcvt_kernel<<<dim3(8, 8, 256), dim3(32, 8), 0, stream>>>(t3, Tbuf, 256);
  bilin256_kernel<<<dim3(16, 256), 512, 0, stream>>>(r12, 512, Tbuf, r12, 512, 256, Lb,
                                                     256, 256, 2, nullptr, 0, 0, (float*)d_out);
}